// Round 6
// baseline (508.791 us; speedup 1.0000x reference)
//
#include <hip/hip_runtime.h>
#include <hip/hip_bf16.h>

typedef __attribute__((ext_vector_type(8))) short bf16x8;
typedef __attribute__((ext_vector_type(4))) float f32x4;
typedef unsigned short ushort_t;
typedef unsigned int uint_t;

#define AS1 __attribute__((address_space(1)))
#define AS3 __attribute__((address_space(3)))

__device__ __forceinline__ void gload_lds16(const void* g, void* l) {
    __builtin_amdgcn_global_load_lds((const AS1 void*)g, (AS3 void*)l, 16, 0, 0);
}

__device__ __forceinline__ ushort_t f2b(float f) {
    unsigned u = __builtin_bit_cast(unsigned, f);
    unsigned r = (u + 0x7FFFu + ((u >> 16) & 1u)) >> 16;
    return (ushort_t)r;
}

// ---------------- convert x (fp32 -> bf16) ----------------
__global__ __launch_bounds__(256) void convert_x_kernel(const float* __restrict__ in,
                                                        ushort_t* __restrict__ out, int n4) {
    int i = blockIdx.x * blockDim.x + threadIdx.x;
    if (i < n4) {
        float4 f = ((const float4*)in)[i];
        ushort4 u;
        u.x = f2b(f.x); u.y = f2b(f.y); u.z = f2b(f.z); u.w = f2b(f.w);
        ((ushort4*)out)[i] = u;
    }
}

// ---------------- transpose + convert weight: W[K][N] fp32 -> WT[N][K] bf16 ----------------
__global__ __launch_bounds__(256) void transpose_w_kernel(const float* __restrict__ W,
                                                          ushort_t* __restrict__ WT) {
    __shared__ float t[32][33];
    int n0 = blockIdx.x * 32, k0 = blockIdx.y * 32;
    int tx = threadIdx.x, ty = threadIdx.y; // block (32,8)
    for (int i = 0; i < 4; ++i)
        t[ty + i * 8][tx] = W[(size_t)(k0 + ty + i * 8) * 1024 + n0 + tx];
    __syncthreads();
    for (int i = 0; i < 4; ++i)
        WT[(size_t)(n0 + ty + i * 8) * 1024 + k0 + tx] = f2b(t[tx][ty + i * 8]);
}

// ---------------- bf16 MFMA GEMM, 2-phase dbuf global_load_lds ----------------
// C[8192][N] = A[8192][1024] @ BT[N][1024]^T.
// MODE 0: fp32 out + bias. MODE 2: QKV fused — cols<2048 bf16 to Cb (stride N),
// cols>=2048 written TRANSPOSED to Vt[b*1024 + (col-2048)][s].
template <int N, int MODE>
__global__ __launch_bounds__(256) void gemm_kernel(const ushort_t* __restrict__ A,
                                                   const ushort_t* __restrict__ BT,
                                                   ushort_t* __restrict__ Cb,
                                                   float* __restrict__ Cf,
                                                   const float* __restrict__ bias,
                                                   ushort_t* __restrict__ Vt) {
    const int K = 1024;
    __shared__ ushort_t As[2 * 128 * 32];
    __shared__ ushort_t Bs[2 * 128 * 32];
    int tid = threadIdx.x;
    int wid = tid >> 6, lane = tid & 63;
    int g = lane >> 4, lr = lane & 15;

    // bijective XCD swizzle (nwg % 8 == 0 for both grids)
    int z = (int)blockIdx.x + 64 * (int)blockIdx.y;
    int nwg = 64 * (int)gridDim.y;
    int zs = (z & 7) * (nwg >> 3) + (z >> 3);
    int m0 = (zs % 64) * 128, n0 = (zs / 64) * 128;

    int wm = wid >> 1, wn = wid & 1;

    f32x4 acc[4][4] = {};

    int c0 = wid * 2;
    int lrow = lane >> 2;
    int lcol = ((lane & 3) ^ ((lane >> 3) & 3)) * 8;
    const ushort_t* Ag0 = A  + (size_t)(m0 + c0 * 16 + lrow) * K + lcol;
    const ushort_t* Ag1 = A  + (size_t)(m0 + c0 * 16 + 16 + lrow) * K + lcol;
    const ushort_t* Bg0 = BT + (size_t)(n0 + c0 * 16 + lrow) * K + lcol;
    const ushort_t* Bg1 = BT + (size_t)(n0 + c0 * 16 + 16 + lrow) * K + lcol;

    int swzA = ((lr >> 1) & 3) << 4;

    auto stage = [&](int bufi, int kt) {
        char* a0 = (char*)As + bufi * 8192 + c0 * 1024;
        char* b0 = (char*)Bs + bufi * 8192 + c0 * 1024;
        gload_lds16(Ag0 + kt * 32, a0);
        gload_lds16(Ag1 + kt * 32, a0 + 1024);
        gload_lds16(Bg0 + kt * 32, b0);
        gload_lds16(Bg1 + kt * 32, b0 + 1024);
    };

    stage(0, 0);
    __syncthreads();
    int buf = 0;
    for (int kt = 0; kt < K / 32; ++kt) {
        if (kt + 1 < K / 32) stage(buf ^ 1, kt + 1);
        const char* ab = (const char*)As + buf * 8192;
        const char* bb = (const char*)Bs + buf * 8192;
        bf16x8 af[4], bfr[4];
#pragma unroll
        for (int m = 0; m < 4; ++m) {
            int row = wm * 64 + m * 16 + lr;
            af[m] = *(const bf16x8*)(ab + row * 64 + ((g * 16) ^ swzA));
        }
#pragma unroll
        for (int n = 0; n < 4; ++n) {
            int row = wn * 64 + n * 16 + lr;
            bfr[n] = *(const bf16x8*)(bb + row * 64 + ((g * 16) ^ swzA));
        }
#pragma unroll
        for (int m = 0; m < 4; ++m)
#pragma unroll
            for (int n = 0; n < 4; ++n)
                acc[m][n] = __builtin_amdgcn_mfma_f32_16x16x32_bf16(af[m], bfr[n], acc[m][n], 0, 0, 0);
        __syncthreads();
        buf ^= 1;
    }

    if (MODE == 2 && (n0 + wn * 64) >= 2048) {
        // V quarter: write transposed (4 consecutive s pack into one ushort4)
#pragma unroll
        for (int m = 0; m < 4; ++m)
#pragma unroll
            for (int n = 0; n < 4; ++n) {
                int row0 = m0 + wm * 64 + m * 16 + g * 4;      // s global
                int c    = n0 + wn * 64 + n * 16 + lr - 2048;  // h*64+d
                int bb2 = row0 >> 11, sloc = row0 & 2047;
                ushort4 u;
                u.x = f2b(acc[m][n][0]); u.y = f2b(acc[m][n][1]);
                u.z = f2b(acc[m][n][2]); u.w = f2b(acc[m][n][3]);
                *(ushort4*)(Vt + ((size_t)(bb2 * 1024 + c)) * 2048 + sloc) = u;
            }
    } else {
#pragma unroll
        for (int m = 0; m < 4; ++m)
#pragma unroll
            for (int n = 0; n < 4; ++n) {
                int row0 = m0 + wm * 64 + m * 16 + g * 4;
                int col  = n0 + wn * 64 + n * 16 + lr;
#pragma unroll
                for (int r = 0; r < 4; ++r) {
                    float v = acc[m][n][r];
                    if (MODE == 0)
                        Cf[(size_t)(row0 + r) * N + col] = v + bias[col];
                    else
                        Cb[(size_t)(row0 + r) * N + col] = f2b(v);
                }
            }
    }
}

// ---------------- fused attention: swapped-operand QK^T, lane-local P rows ----------------
// grid (32,16,4), 4 waves. Pass 1: 4-slot K ring, 2-deep prefetch, counted
// vmcnt(8) barriers. Pass 2: K/V dbuf 1-deep + counted vmcnt(4) (P stores linger).
__global__ __launch_bounds__(256) void attn_kernel(const ushort_t* __restrict__ Cqkv,
                                                   const ushort_t* __restrict__ Vtg,
                                                   float* __restrict__ Pout,
                                                   ushort_t* __restrict__ Oout) {
    const int S = 2048, DQ = 3072;
    const float C1 = 0.18033688f;   // 0.125 * log2(e)
    const float C2 = 5.77078016f;   // 4 * log2(e)

    int z = (int)blockIdx.x + 32 * (int)blockIdx.y + 512 * (int)blockIdx.z;
    int h = (z >> 5) & 15, b = z >> 9;
    int qt = ((z & 31) + 13 * ((z >> 8) & 7)) & 31;   // balanced bijection
    int q0 = qt * 64;

    int tid = threadIdx.x, wid = tid >> 6, lane = tid & 63;
    int g = lane >> 4, lr = lane & 15;

    __shared__ ushort_t KV[4][4096];   // pass1: 4-slot K ring; pass2: K={0,1}, V={2,3}
    __shared__ ushort_t Pl[4096];      // 4 waves x [16 q][64 t] bf16
    char* PlB = (char*)Pl + wid * 2048;

    const ushort_t* Qb = Cqkv + (size_t)b * S * DQ + (size_t)h * 64;
    const ushort_t* Kb = Cqkv + (size_t)b * S * DQ + 1024 + (size_t)h * 64;
    const ushort_t* Vb = Vtg + (size_t)((b * 16 + h) * 64) * 2048;
    float* Pbase = Pout + (((size_t)(b * 16 + h)) * S + q0) * S;

    // staging geometry: tile 64 rows x 128B; lane covers 16B; wave w owns rows w*8..w*8+7 (+32)
    int srow = lane >> 3;
    int scol = ((lane & 7) ^ srow) * 8;   // pre-swizzled source chunk

    auto stageK = [&](int ri, int tt) {
        char* dst = (char*)&KV[ri][0] + wid * 1024;
        gload_lds16(Kb + (size_t)(tt * 64 + wid * 8 + srow) * DQ + scol, dst);
        gload_lds16(Kb + (size_t)(tt * 64 + 32 + wid * 8 + srow) * DQ + scol, dst + 4096);
    };
    auto stageV = [&](int ri, int tt) {
        char* dst = (char*)&KV[2 + ri][0] + wid * 1024;
        gload_lds16(Vb + (size_t)(wid * 8 + srow) * 2048 + tt * 64 + scol, dst);
        gload_lds16(Vb + (size_t)(32 + wid * 8 + srow) * 2048 + tt * 64 + scol, dst + 4096);
    };

    // Q fragments (registers, whole kernel) — B-operand: col=lr -> q row
    bf16x8 qf[2];
    {
        const ushort_t* qp = Qb + (size_t)(q0 + wid * 16 + lr) * DQ + g * 8;
        qf[0] = *(const bf16x8*)qp;
        qf[1] = *(const bf16x8*)(qp + 32);
    }
    int qloc = wid * 16 + lr;   // this lane's q row (local 0..63)

    // ---- pass 1: per-lane sum of exp2(s*C1 - C2); 2-deep prefetch, vmcnt(8) ----
    float psum = 0.f;
    stageK(0, 0);
    stageK(1, qt >= 1 ? 1 : 0);
    asm volatile("s_waitcnt vmcnt(8)" ::: "memory");
    __builtin_amdgcn_s_barrier();
    __builtin_amdgcn_sched_barrier(0);
    for (int tt = 0; tt <= qt; ++tt) {
        int nt = tt + 2;
        stageK(nt & 3, nt <= qt ? nt : qt);   // dummy re-stage at tail keeps count uniform
        const char* ksb = (const char*)&KV[tt & 3][0];
        __builtin_amdgcn_s_setprio(1);
#pragma unroll
        for (int nb = 0; nb < 4; ++nb) {
            int row = nb * 16 + lr;
            int x = (row & 7) << 4;
            f32x4 s = {};
            s = __builtin_amdgcn_mfma_f32_16x16x32_bf16(*(const bf16x8*)(ksb + row * 128 + ((g * 16) ^ x)), qf[0], s, 0, 0, 0);
            s = __builtin_amdgcn_mfma_f32_16x16x32_bf16(*(const bf16x8*)(ksb + row * 128 + ((64 + g * 16) ^ x)), qf[1], s, 0, 0, 0);
            if (tt == qt) {
#pragma unroll
                for (int r = 0; r < 4; ++r)
                    if (nb * 16 + g * 4 + r <= qloc) psum += exp2f(fmaf(s[r], C1, -C2));
            } else {
#pragma unroll
                for (int r = 0; r < 4; ++r) psum += exp2f(fmaf(s[r], C1, -C2));
            }
        }
        __builtin_amdgcn_s_setprio(0);
        asm volatile("s_waitcnt vmcnt(8)" ::: "memory");
        __builtin_amdgcn_s_barrier();
        __builtin_amdgcn_sched_barrier(0);
    }
    psum += __shfl_xor(psum, 16);
    psum += __shfl_xor(psum, 32);
    float lnl2 = __log2f(psum) + C2;

    // ---- pass 2: P = exp2(s*C1 - lnl2); direct f32 stores; LDS repack for PV ----
    f32x4 Oacc[4] = {};
    stageK(0, 0);
    stageV(0, 0);
    __syncthreads();   // full drain (incl. pass-1 leftovers)
    int buf = 0;
    for (int tt = 0; tt <= qt; ++tt) {
        if (tt < qt) { stageK(buf ^ 1, tt + 1); stageV(buf ^ 1, tt + 1); }
        const char* ksb = (const char*)&KV[buf][0];
        const char* vsb = (const char*)&KV[2 + buf][0];
        f32x4 p[4];
        __builtin_amdgcn_s_setprio(1);
#pragma unroll
        for (int nb = 0; nb < 4; ++nb) {
            int row = nb * 16 + lr;
            int x = (row & 7) << 4;
            f32x4 s = {};
            s = __builtin_amdgcn_mfma_f32_16x16x32_bf16(*(const bf16x8*)(ksb + row * 128 + ((g * 16) ^ x)), qf[0], s, 0, 0, 0);
            s = __builtin_amdgcn_mfma_f32_16x16x32_bf16(*(const bf16x8*)(ksb + row * 128 + ((64 + g * 16) ^ x)), qf[1], s, 0, 0, 0);
#pragma unroll
            for (int r = 0; r < 4; ++r) {
                float v = exp2f(fmaf(s[r], C1, -lnl2));
                if (tt == qt && (nb * 16 + g * 4 + r > qloc)) v = 0.f;
                p[nb][r] = v;
            }
        }
        __builtin_amdgcn_s_setprio(0);
        // direct P global stores (f32, 64B/row per wave, fully coalesced)
#pragma unroll
        for (int nb = 0; nb < 4; ++nb)
            *(f32x4*)(Pbase + (size_t)qloc * S + tt * 64 + nb * 16 + g * 4) = p[nb];
        // pack to bf16 and repack via tiny LDS tile (wave-private)
#pragma unroll
        for (int nb = 0; nb < 4; ++nb) {
            uint_t w0, w1;
            asm("v_cvt_pk_bf16_f32 %0, %1, %2" : "=v"(w0) : "v"(p[nb][0]), "v"(p[nb][1]));
            asm("v_cvt_pk_bf16_f32 %0, %1, %2" : "=v"(w1) : "v"(p[nb][2]), "v"(p[nb][3]));
            uint2 w; w.x = w0; w.y = w1;
            *(uint2*)(PlB + ((lr * 128 + nb * 32 + g * 8) ^ ((lr & 7) << 4))) = w;
        }
        __builtin_amdgcn_wave_barrier();
        // PV MFMA: A = repacked P rows, B = V fragments from LDS
        __builtin_amdgcn_s_setprio(1);
#pragma unroll
        for (int kc = 0; kc < 2; ++kc) {
            bf16x8 pf = *(const bf16x8*)(PlB + ((lr * 128 + kc * 64 + g * 16) ^ ((lr & 7) << 4)));
#pragma unroll
            for (int nb = 0; nb < 4; ++nb) {
                int vrow = nb * 16 + lr;
                bf16x8 vf = *(const bf16x8*)(vsb + vrow * 128 + ((kc * 64 + g * 16) ^ ((vrow & 7) << 4)));
                Oacc[nb] = __builtin_amdgcn_mfma_f32_16x16x32_bf16(pf, vf, Oacc[nb], 0, 0, 0);
            }
        }
        __builtin_amdgcn_s_setprio(0);
        // counted drain: K/V prefetch loads must land; the 4 newest P stores may linger
        asm volatile("s_waitcnt vmcnt(4)" ::: "memory");
        __builtin_amdgcn_s_barrier();
        __builtin_amdgcn_sched_barrier(0);
        buf ^= 1;
    }

    // zero-fill strictly-upper tiles
    {
        int vsr = tid >> 2, vsc = (tid & 3) * 16;
        float4 zf = {0.f, 0.f, 0.f, 0.f};
        for (int tt = qt + 1; tt < 32; ++tt) {
            float* dst = Pbase + (size_t)vsr * S + tt * 64 + vsc;
#pragma unroll
            for (int j = 0; j < 4; ++j) ((float4*)dst)[j] = zf;
        }
    }

    // write O (bf16) as [B,S,H*Dh]
#pragma unroll
    for (int nb = 0; nb < 4; ++nb)
#pragma unroll
        for (int r = 0; r < 4; ++r) {
            int q = q0 + wid * 16 + g * 4 + r;
            Oout[((size_t)b * S + q) * 1024 + h * 64 + nb * 16 + lr] = f2b(Oacc[nb][r]);
        }
}

extern "C" void kernel_launch(void* const* d_in, const int* in_sizes, int n_in,
                              void* d_out, int out_size, void* d_ws, size_t ws_size,
                              hipStream_t stream) {
    const float* x  = (const float*)d_in[0];
    const float* Wq = (const float*)d_in[1];
    const float* Wk = (const float*)d_in[2];
    const float* Wv = (const float*)d_in[3];
    const float* Wo = (const float*)d_in[4];
    const float* bo = (const float*)d_in[5];

    float* out  = (float*)d_out;
    float* Pout = out + (size_t)8388608; // attn_probs region

    char* ws = (char*)d_ws;
    ushort_t* xb    = (ushort_t*)(ws);                       // 16 MB
    ushort_t* wqkv  = (ushort_t*)(ws + (16u << 20));         // 6 MB [3072][1024]
    ushort_t* wob   = (ushort_t*)(ws + (22u << 20));         // 2 MB
    ushort_t* Cqkv  = (ushort_t*)(ws + (24u << 20));         // 48 MB [8192][3072] (V third unused)
    ushort_t* Vtw   = (ushort_t*)(ws + (72u << 20));         // 32 MB [b*1024 + h*64+d][2048]
    ushort_t* attnb = (ushort_t*)(ws + (104u << 20));        // 16 MB

    // 1. dtype conversions / weight transposes
    convert_x_kernel<<<8192, 256, 0, stream>>>(x, xb, 2097152);
    transpose_w_kernel<<<dim3(32, 32), dim3(32, 8), 0, stream>>>(Wq, wqkv);
    transpose_w_kernel<<<dim3(32, 32), dim3(32, 8), 0, stream>>>(Wk, wqkv + 1024 * 1024);
    transpose_w_kernel<<<dim3(32, 32), dim3(32, 8), 0, stream>>>(Wv, wqkv + 2 * 1024 * 1024);
    transpose_w_kernel<<<dim3(32, 32), dim3(32, 8), 0, stream>>>(Wo, wob);

    // 2. fused QKV projection; V written transposed straight to Vtw
    gemm_kernel<3072, 2><<<dim3(64, 24), 256, 0, stream>>>(xb, wqkv, Cqkv, nullptr, nullptr, Vtw);

    // 3. attention (writes attn_probs fp32 + context bf16)
    attn_kernel<<<dim3(32, 16, 4), 256, 0, stream>>>(Cqkv, Vtw, Pout, attnb);

    // 4. output projection + bias (fp32 out)
    gemm_kernel<1024, 0><<<dim3(64, 8), 256, 0, stream>>>(attnb, wob, nullptr, out, bo, nullptr);
}

// Round 7
// 479.030 us; speedup vs baseline: 1.0621x; 1.0621x over previous
//
#include <hip/hip_runtime.h>
#include <hip/hip_bf16.h>

typedef __attribute__((ext_vector_type(8))) short bf16x8;
typedef __attribute__((ext_vector_type(4))) float f32x4;
typedef unsigned short ushort_t;
typedef unsigned int uint_t;

#define AS1 __attribute__((address_space(1)))
#define AS3 __attribute__((address_space(3)))

__constant__ int P4tab[16] = {0, 5, 10, 15, 1, 4, 11, 14, 2, 7, 8, 13, 3, 6, 9, 12};

__device__ __forceinline__ void gload_lds16(const void* g, void* l) {
    __builtin_amdgcn_global_load_lds((const AS1 void*)g, (AS3 void*)l, 16, 0, 0);
}

__device__ __forceinline__ ushort_t f2b(float f) {
    unsigned u = __builtin_bit_cast(unsigned, f);
    unsigned r = (u + 0x7FFFu + ((u >> 16) & 1u)) >> 16;
    return (ushort_t)r;
}

// ---------------- convert x (fp32 -> bf16) ----------------
__global__ __launch_bounds__(256) void convert_x_kernel(const float* __restrict__ in,
                                                        ushort_t* __restrict__ out, int n4) {
    int i = blockIdx.x * blockDim.x + threadIdx.x;
    if (i < n4) {
        float4 f = ((const float4*)in)[i];
        ushort4 u;
        u.x = f2b(f.x); u.y = f2b(f.y); u.z = f2b(f.z); u.w = f2b(f.w);
        ((ushort4*)out)[i] = u;
    }
}

// ---------------- transpose + convert weight: W[K][N] fp32 -> WT[N][K] bf16 ----------------
__global__ __launch_bounds__(256) void transpose_w_kernel(const float* __restrict__ W,
                                                          ushort_t* __restrict__ WT) {
    __shared__ float t[32][33];
    int n0 = blockIdx.x * 32, k0 = blockIdx.y * 32;
    int tx = threadIdx.x, ty = threadIdx.y; // block (32,8)
    for (int i = 0; i < 4; ++i)
        t[ty + i * 8][tx] = W[(size_t)(k0 + ty + i * 8) * 1024 + n0 + tx];
    __syncthreads();
    for (int i = 0; i < 4; ++i)
        WT[(size_t)(n0 + ty + i * 8) * 1024 + k0 + tx] = f2b(t[tx][ty + i * 8]);
}

// ---------------- bf16 MFMA GEMM, 2-phase dbuf global_load_lds ----------------
template <int N, int OUT_BF16>
__global__ __launch_bounds__(256) void gemm_kernel(const ushort_t* __restrict__ A,
                                                   const ushort_t* __restrict__ BT,
                                                   ushort_t* __restrict__ Cb,
                                                   float* __restrict__ Cf,
                                                   const float* __restrict__ bias) {
    const int K = 1024;
    __shared__ ushort_t As[2 * 128 * 32];
    __shared__ ushort_t Bs[2 * 128 * 32];
    int tid = threadIdx.x;
    int wid = tid >> 6, lane = tid & 63;
    int g = lane >> 4, lr = lane & 15;
    int m0 = blockIdx.x * 128, n0 = blockIdx.y * 128;
    int wm = wid >> 1, wn = wid & 1;

    f32x4 acc[4][4] = {};

    int c0 = wid * 2;
    int lrow = lane >> 2;
    int lcol = ((lane & 3) ^ ((lane >> 3) & 3)) * 8;
    const ushort_t* Ag0 = A  + (size_t)(m0 + c0 * 16 + lrow) * K + lcol;
    const ushort_t* Ag1 = A  + (size_t)(m0 + c0 * 16 + 16 + lrow) * K + lcol;
    const ushort_t* Bg0 = BT + (size_t)(n0 + c0 * 16 + lrow) * K + lcol;
    const ushort_t* Bg1 = BT + (size_t)(n0 + c0 * 16 + 16 + lrow) * K + lcol;

    int swzA = ((lr >> 1) & 3) << 4;

    auto stage = [&](int bufi, int kt) {
        char* a0 = (char*)As + bufi * 8192 + c0 * 1024;
        char* b0 = (char*)Bs + bufi * 8192 + c0 * 1024;
        gload_lds16(Ag0 + kt * 32, a0);
        gload_lds16(Ag1 + kt * 32, a0 + 1024);
        gload_lds16(Bg0 + kt * 32, b0);
        gload_lds16(Bg1 + kt * 32, b0 + 1024);
    };

    stage(0, 0);
    __syncthreads();
    int buf = 0;
    for (int kt = 0; kt < K / 32; ++kt) {
        if (kt + 1 < K / 32) stage(buf ^ 1, kt + 1);
        const char* ab = (const char*)As + buf * 8192;
        const char* bb = (const char*)Bs + buf * 8192;
        bf16x8 af[4], bfr[4];
#pragma unroll
        for (int m = 0; m < 4; ++m) {
            int row = wm * 64 + m * 16 + lr;
            af[m] = *(const bf16x8*)(ab + row * 64 + ((g * 16) ^ swzA));
        }
#pragma unroll
        for (int n = 0; n < 4; ++n) {
            int row = wn * 64 + n * 16 + lr;
            bfr[n] = *(const bf16x8*)(bb + row * 64 + ((g * 16) ^ swzA));
        }
#pragma unroll
        for (int m = 0; m < 4; ++m)
#pragma unroll
            for (int n = 0; n < 4; ++n)
                acc[m][n] = __builtin_amdgcn_mfma_f32_16x16x32_bf16(af[m], bfr[n], acc[m][n], 0, 0, 0);
        __syncthreads();
        buf ^= 1;
    }

#pragma unroll
    for (int m = 0; m < 4; ++m)
#pragma unroll
        for (int n = 0; n < 4; ++n) {
            int row0 = m0 + wm * 64 + m * 16 + g * 4;
            int col  = n0 + wn * 64 + n * 16 + lr;
#pragma unroll
            for (int r = 0; r < 4; ++r) {
                float v = acc[m][n][r];
                if (OUT_BF16)
                    Cb[(size_t)(row0 + r) * N + col] = f2b(v);
                else
                    Cf[(size_t)(row0 + r) * N + col] = v + bias[col];
            }
        }
}

// ---------------- V transpose: Cqkv V-part [s][d] -> Vt[b][h][d][s] bf16 ----------------
__global__ __launch_bounds__(256) void vt_kernel(const ushort_t* __restrict__ Cqkv,
                                                 ushort_t* __restrict__ Vt) {
    int b = blockIdx.z, h = blockIdx.y, st = blockIdx.x;
    __shared__ ushort_t t[64][72];
    const ushort_t* src = Cqkv + (size_t)b * 2048 * 3072 + 2048 + (size_t)h * 64;
    int tid = threadIdx.x;
#pragma unroll
    for (int i = 0; i < 2; ++i) {
        int c = tid + i * 256;
        int sl = c >> 3, dc = (c & 7) * 8;
        *(bf16x8*)&t[sl][dc] = *(const bf16x8*)(src + (size_t)(st * 64 + sl) * 3072 + dc);
    }
    __syncthreads();
#pragma unroll
    for (int i = 0; i < 2; ++i) {
        int c = tid + i * 256;
        int d = c >> 3, sc = (c & 7) * 8;
        bf16x8 v;
#pragma unroll
        for (int j = 0; j < 8; ++j) v[j] = (short)t[sc + j][d];
        *(bf16x8*)(Vt + ((size_t)(b * 16 + h) * 64 + d) * 2048 + st * 64 + sc) = v;
    }
}

// ---------------- fused attention: paired q-tiles (p, 31-p), merged passes ----------------
// grid 1024 blocks, 4 waves. qtA = p <= 15 < qtB = 31-p, so tile A's K/V range is a
// subset of B's: one sweep stages K/V once and computes both tiles.
__global__ __launch_bounds__(256, 4) void attn_kernel(const ushort_t* __restrict__ Cqkv,
                                                      const ushort_t* __restrict__ Vtg,
                                                      float* __restrict__ Pout,
                                                      ushort_t* __restrict__ Oout) {
    const int S = 2048, DQ = 3072;
    const float C1 = 0.18033688f;   // 0.125 * log2(e)
    const float C2 = 5.77078016f;   // 4 * log2(e)

    int z = (int)blockIdx.x;
    int c = z & 255, j = z >> 8;
    int p = P4tab[(c & 3) * 4 + j];   // equal-sum pairing per CU
    int h = (c >> 2) & 15, b = c >> 6;
    int qtA = p, qtB = 31 - p;

    int tid = threadIdx.x, wid = tid >> 6, lane = tid & 63;
    int g = lane >> 4, lr = lane & 15;

    __shared__ ushort_t KV[4][4096];   // K dbuf {0,1}, V dbuf {2,3}
    __shared__ ushort_t Pl[4096];      // 4 waves x [16 q][64 t] bf16 (A/B sequential)
    char* PlB = (char*)Pl + wid * 2048;

    const ushort_t* Qb = Cqkv + (size_t)b * S * DQ + (size_t)h * 64;
    const ushort_t* Kb = Cqkv + (size_t)b * S * DQ + 1024 + (size_t)h * 64;
    const ushort_t* Vb = Vtg + (size_t)((b * 16 + h) * 64) * 2048;
    float* PbaseA = Pout + (((size_t)(b * 16 + h)) * S + qtA * 64) * S;
    float* PbaseB = Pout + (((size_t)(b * 16 + h)) * S + qtB * 64) * S;

    int srow = lane >> 3;
    int scol = ((lane & 7) ^ srow) * 8;   // pre-swizzled source chunk

    auto stageK = [&](int ri, int tt) {
        char* dst = (char*)&KV[ri][0] + wid * 1024;
        gload_lds16(Kb + (size_t)(tt * 64 + wid * 8 + srow) * DQ + scol, dst);
        gload_lds16(Kb + (size_t)(tt * 64 + 32 + wid * 8 + srow) * DQ + scol, dst + 4096);
    };
    auto stageV = [&](int ri, int tt) {
        char* dst = (char*)&KV[2 + ri][0] + wid * 1024;
        gload_lds16(Vb + (size_t)(wid * 8 + srow) * 2048 + tt * 64 + scol, dst);
        gload_lds16(Vb + (size_t)(32 + wid * 8 + srow) * 2048 + tt * 64 + scol, dst + 4096);
    };

    // Q fragments for both tiles (B-operand: col=lr -> q row)
    bf16x8 qfA[2], qfB[2];
    {
        const ushort_t* qa = Qb + (size_t)(qtA * 64 + wid * 16 + lr) * DQ + g * 8;
        qfA[0] = *(const bf16x8*)qa;
        qfA[1] = *(const bf16x8*)(qa + 32);
        const ushort_t* qb2 = Qb + (size_t)(qtB * 64 + wid * 16 + lr) * DQ + g * 8;
        qfB[0] = *(const bf16x8*)qb2;
        qfB[1] = *(const bf16x8*)(qb2 + 32);
    }
    int qloc = wid * 16 + lr;   // this lane's q row (local 0..63)

    // ---- pass 1 (merged): per-lane sums of exp2(s*C1 - C2) for A and B ----
    float psA = 0.f, psB = 0.f;
    stageK(0, 0);
    __syncthreads();
    int buf = 0;
    for (int tt = 0; tt <= qtB; ++tt) {
        if (tt < qtB) stageK(buf ^ 1, tt + 1);
        const char* ksb = (const char*)&KV[buf][0];
#pragma unroll
        for (int nb = 0; nb < 4; ++nb) {
            int row = nb * 16 + lr;
            int x = (row & 7) << 4;
            bf16x8 k0 = *(const bf16x8*)(ksb + row * 128 + ((g * 16) ^ x));
            bf16x8 k1 = *(const bf16x8*)(ksb + row * 128 + ((64 + g * 16) ^ x));
            f32x4 sB = {};
            sB = __builtin_amdgcn_mfma_f32_16x16x32_bf16(k0, qfB[0], sB, 0, 0, 0);
            sB = __builtin_amdgcn_mfma_f32_16x16x32_bf16(k1, qfB[1], sB, 0, 0, 0);
            if (tt == qtB) {
#pragma unroll
                for (int r = 0; r < 4; ++r)
                    if (nb * 16 + g * 4 + r <= qloc) psB += exp2f(fmaf(sB[r], C1, -C2));
            } else {
#pragma unroll
                for (int r = 0; r < 4; ++r) psB += exp2f(fmaf(sB[r], C1, -C2));
            }
            if (tt <= qtA) {
                f32x4 sA = {};
                sA = __builtin_amdgcn_mfma_f32_16x16x32_bf16(k0, qfA[0], sA, 0, 0, 0);
                sA = __builtin_amdgcn_mfma_f32_16x16x32_bf16(k1, qfA[1], sA, 0, 0, 0);
                if (tt == qtA) {
#pragma unroll
                    for (int r = 0; r < 4; ++r)
                        if (nb * 16 + g * 4 + r <= qloc) psA += exp2f(fmaf(sA[r], C1, -C2));
                } else {
#pragma unroll
                    for (int r = 0; r < 4; ++r) psA += exp2f(fmaf(sA[r], C1, -C2));
                }
            }
        }
        __syncthreads();
        buf ^= 1;
    }
    psA += __shfl_xor(psA, 16); psA += __shfl_xor(psA, 32);
    psB += __shfl_xor(psB, 16); psB += __shfl_xor(psB, 32);
    float lnA = __log2f(psA) + C2;
    float lnB = __log2f(psB) + C2;

    // ---- pass 2 (merged): P + PV for B always, A when tt<=qtA ----
    f32x4 OA[4] = {}, OB[4] = {};
    stageK(0, 0);
    stageV(0, 0);
    __syncthreads();
    buf = 0;
    for (int tt = 0; tt <= qtB; ++tt) {
        if (tt < qtB) { stageK(buf ^ 1, tt + 1); stageV(buf ^ 1, tt + 1); }
        const char* ksb = (const char*)&KV[buf][0];
        const char* vsb = (const char*)&KV[2 + buf][0];

        // ----- tile B -----
        {
            f32x4 pv[4];
#pragma unroll
            for (int nb = 0; nb < 4; ++nb) {
                int row = nb * 16 + lr;
                int x = (row & 7) << 4;
                f32x4 s = {};
                s = __builtin_amdgcn_mfma_f32_16x16x32_bf16(*(const bf16x8*)(ksb + row * 128 + ((g * 16) ^ x)), qfB[0], s, 0, 0, 0);
                s = __builtin_amdgcn_mfma_f32_16x16x32_bf16(*(const bf16x8*)(ksb + row * 128 + ((64 + g * 16) ^ x)), qfB[1], s, 0, 0, 0);
#pragma unroll
                for (int r = 0; r < 4; ++r) {
                    float v = exp2f(fmaf(s[r], C1, -lnB));
                    if (tt == qtB && (nb * 16 + g * 4 + r > qloc)) v = 0.f;
                    pv[nb][r] = v;
                }
            }
#pragma unroll
            for (int nb = 0; nb < 4; ++nb)
                *(f32x4*)(PbaseB + (size_t)qloc * S + tt * 64 + nb * 16 + g * 4) = pv[nb];
#pragma unroll
            for (int nb = 0; nb < 4; ++nb) {
                uint_t w0, w1;
                asm("v_cvt_pk_bf16_f32 %0, %1, %2" : "=v"(w0) : "v"(pv[nb][0]), "v"(pv[nb][1]));
                asm("v_cvt_pk_bf16_f32 %0, %1, %2" : "=v"(w1) : "v"(pv[nb][2]), "v"(pv[nb][3]));
                uint2 w; w.x = w0; w.y = w1;
                *(uint2*)(PlB + ((lr * 128 + nb * 32 + g * 8) ^ ((lr & 7) << 4))) = w;
            }
            __builtin_amdgcn_wave_barrier();
#pragma unroll
            for (int kc = 0; kc < 2; ++kc) {
                bf16x8 pf = *(const bf16x8*)(PlB + ((lr * 128 + kc * 64 + g * 16) ^ ((lr & 7) << 4)));
#pragma unroll
                for (int nb = 0; nb < 4; ++nb) {
                    int vrow = nb * 16 + lr;
                    bf16x8 vf = *(const bf16x8*)(vsb + vrow * 128 + ((kc * 64 + g * 16) ^ ((vrow & 7) << 4)));
                    OB[nb] = __builtin_amdgcn_mfma_f32_16x16x32_bf16(pf, vf, OB[nb], 0, 0, 0);
                }
            }
            __builtin_amdgcn_wave_barrier();
        }

        // ----- tile A (subset range) -----
        if (tt <= qtA) {
            f32x4 pv[4];
#pragma unroll
            for (int nb = 0; nb < 4; ++nb) {
                int row = nb * 16 + lr;
                int x = (row & 7) << 4;
                f32x4 s = {};
                s = __builtin_amdgcn_mfma_f32_16x16x32_bf16(*(const bf16x8*)(ksb + row * 128 + ((g * 16) ^ x)), qfA[0], s, 0, 0, 0);
                s = __builtin_amdgcn_mfma_f32_16x16x32_bf16(*(const bf16x8*)(ksb + row * 128 + ((64 + g * 16) ^ x)), qfA[1], s, 0, 0, 0);
#pragma unroll
                for (int r = 0; r < 4; ++r) {
                    float v = exp2f(fmaf(s[r], C1, -lnA));
                    if (tt == qtA && (nb * 16 + g * 4 + r > qloc)) v = 0.f;
                    pv[nb][r] = v;
                }
            }
#pragma unroll
            for (int nb = 0; nb < 4; ++nb)
                *(f32x4*)(PbaseA + (size_t)qloc * S + tt * 64 + nb * 16 + g * 4) = pv[nb];
#pragma unroll
            for (int nb = 0; nb < 4; ++nb) {
                uint_t w0, w1;
                asm("v_cvt_pk_bf16_f32 %0, %1, %2" : "=v"(w0) : "v"(pv[nb][0]), "v"(pv[nb][1]));
                asm("v_cvt_pk_bf16_f32 %0, %1, %2" : "=v"(w1) : "v"(pv[nb][2]), "v"(pv[nb][3]));
                uint2 w; w.x = w0; w.y = w1;
                *(uint2*)(PlB + ((lr * 128 + nb * 32 + g * 8) ^ ((lr & 7) << 4))) = w;
            }
            __builtin_amdgcn_wave_barrier();
#pragma unroll
            for (int kc = 0; kc < 2; ++kc) {
                bf16x8 pf = *(const bf16x8*)(PlB + ((lr * 128 + kc * 64 + g * 16) ^ ((lr & 7) << 4)));
#pragma unroll
                for (int nb = 0; nb < 4; ++nb) {
                    int vrow = nb * 16 + lr;
                    bf16x8 vf = *(const bf16x8*)(vsb + vrow * 128 + ((kc * 64 + g * 16) ^ ((vrow & 7) << 4)));
                    OA[nb] = __builtin_amdgcn_mfma_f32_16x16x32_bf16(pf, vf, OA[nb], 0, 0, 0);
                }
            }
            __builtin_amdgcn_wave_barrier();
            // drain the 4 stage loads; allow up to 8 P stores (B + A) to linger
            asm volatile("s_waitcnt vmcnt(8)" ::: "memory");
        } else {
            asm volatile("s_waitcnt vmcnt(4)" ::: "memory");
        }
        __builtin_amdgcn_s_barrier();
        __builtin_amdgcn_sched_barrier(0);
        buf ^= 1;
    }

    // zero-fill strictly-upper tiles for both bands (31 tiles total, uniform)
    {
        int vsr = tid >> 2, vsc = (tid & 3) * 16;
        float4 zf = {0.f, 0.f, 0.f, 0.f};
        for (int tt = qtA + 1; tt < 32; ++tt) {
            float* dst = PbaseA + (size_t)vsr * S + tt * 64 + vsc;
#pragma unroll
            for (int jj = 0; jj < 4; ++jj) ((float4*)dst)[jj] = zf;
        }
        for (int tt = qtB + 1; tt < 32; ++tt) {
            float* dst = PbaseB + (size_t)vsr * S + tt * 64 + vsc;
#pragma unroll
            for (int jj = 0; jj < 4; ++jj) ((float4*)dst)[jj] = zf;
        }
    }

    // write O (bf16) as [B,S,H*Dh] for both tiles
#pragma unroll
    for (int nb = 0; nb < 4; ++nb)
#pragma unroll
        for (int r = 0; r < 4; ++r) {
            int qA = qtA * 64 + wid * 16 + g * 4 + r;
            int qB = qtB * 64 + wid * 16 + g * 4 + r;
            Oout[((size_t)b * S + qA) * 1024 + h * 64 + nb * 16 + lr] = f2b(OA[nb][r]);
            Oout[((size_t)b * S + qB) * 1024 + h * 64 + nb * 16 + lr] = f2b(OB[nb][r]);
        }
}

extern "C" void kernel_launch(void* const* d_in, const int* in_sizes, int n_in,
                              void* d_out, int out_size, void* d_ws, size_t ws_size,
                              hipStream_t stream) {
    const float* x  = (const float*)d_in[0];
    const float* Wq = (const float*)d_in[1];
    const float* Wk = (const float*)d_in[2];
    const float* Wv = (const float*)d_in[3];
    const float* Wo = (const float*)d_in[4];
    const float* bo = (const float*)d_in[5];

    float* out  = (float*)d_out;
    float* Pout = out + (size_t)8388608; // attn_probs region

    char* ws = (char*)d_ws;
    ushort_t* xb    = (ushort_t*)(ws);                       // 16 MB
    ushort_t* wqkv  = (ushort_t*)(ws + (16u << 20));         // 6 MB [3072][1024]
    ushort_t* wob   = (ushort_t*)(ws + (22u << 20));         // 2 MB
    ushort_t* Cqkv  = (ushort_t*)(ws + (24u << 20));         // 48 MB [8192][3072]
    ushort_t* Vtw   = (ushort_t*)(ws + (72u << 20));         // 32 MB [b*16+h][64][2048]
    ushort_t* attnb = (ushort_t*)(ws + (104u << 20));        // 16 MB

    // 1. dtype conversions / weight transposes
    convert_x_kernel<<<8192, 256, 0, stream>>>(x, xb, 2097152);
    transpose_w_kernel<<<dim3(32, 32), dim3(32, 8), 0, stream>>>(Wq, wqkv);
    transpose_w_kernel<<<dim3(32, 32), dim3(32, 8), 0, stream>>>(Wk, wqkv + 1024 * 1024);
    transpose_w_kernel<<<dim3(32, 32), dim3(32, 8), 0, stream>>>(Wv, wqkv + 2 * 1024 * 1024);
    transpose_w_kernel<<<dim3(32, 32), dim3(32, 8), 0, stream>>>(Wo, wob);

    // 2. fused QKV projection: Cqkv[8192][3072]
    gemm_kernel<3072, 1><<<dim3(64, 24), 256, 0, stream>>>(xb, wqkv, Cqkv, nullptr, nullptr);

    // 3. V transpose to [b][h][d][s]
    vt_kernel<<<dim3(32, 16, 4), 256, 0, stream>>>(Cqkv, Vtw);

    // 4. attention, paired q-tiles (writes attn_probs fp32 + context bf16)
    attn_kernel<<<1024, 256, 0, stream>>>(Cqkv, Vtw, Pout, attnb);

    // 5. output projection + bias (fp32 out)
    gemm_kernel<1024, 0><<<dim3(64, 8), 256, 0, stream>>>(attnb, wob, nullptr, out, bo);
}